// Round 10
// baseline (4720.617 us; speedup 1.0000x reference)
//
#include <hip/hip_runtime.h>
#include <hip/hip_fp16.h>
#include <math.h>

// ---------------------------------------------------------------------------
// RelationExtractionModel B=64,T=256. Round 10: single persistent k_tree
// kernel (64 blocks = 1/batch) replaces k_leaves + 24 tree-loop dispatches +
// k_classifier. h ping-pong in LDS f16, c via global (thread-private column),
// f32 U weights streamed from L2. LSTM/GEMM stack unchanged from round 9.
// ---------------------------------------------------------------------------

typedef _Float16 h2v  __attribute__((ext_vector_type(2)));
typedef _Float16 f16x8 __attribute__((ext_vector_type(8)));
typedef float    f32x4 __attribute__((ext_vector_type(4)));

union PK { _Float16 h[8]; unsigned long long u64[2]; f16x8 v; };

__device__ __forceinline__ float sigm(float x) { return 1.0f / (1.0f + expf(-x)); }

struct EmbArgs {
  const float* tf; const int* pos_ids; const int* dep_ids;
  const int* e1; const int* e2; const int* sdp;
  const float* pos_tab; const float* dep_tab; const float* dist_tab;
  const float* sdp_tab;
};

// ---------------- weight pack: BT[n*Kpad+k] = f16(W[k*N+n]) ----------------
__global__ __launch_bounds__(256) void k_packB(const float* __restrict__ W,
                                               __half* __restrict__ BT,
                                               int N, int Kpad) {
  int k = blockIdx.x;
  int n = blockIdx.y * 256 + threadIdx.x;
  BT[(size_t)n * Kpad + k] = __float2half_rn(W[(size_t)k * N + n]);
}
__global__ __launch_bounds__(256) void k_zft(__half* __restrict__ BT) {
  int i = blockIdx.x * 256 + threadIdx.x;  // 512 rows x 16 pad cols
  int n = i >> 4, kk = i & 15;
  BT[(size_t)n * 928 + 912 + kk] = __float2half_rn(0.0f);
}

// ---- LSTM weight pack (8 slices of 32 units):
// WB[((j*128 + c)*256) + k] = f16(Whh[k][ (c&3)*256 + j*32 + (c>>2) ])
__global__ __launch_bounds__(256) void k_packWB(const float* __restrict__ W,
                                                __half* __restrict__ WB) {
  int i = blockIdx.x * 256 + threadIdx.x;  // 0..262143
  int k = i & 255;
  int c = (i >> 8) & 127;
  int j = i >> 15;
  int col = (c & 3) * 256 + j * 32 + (c >> 2);
  WB[i] = __float2half_rn(W[(size_t)k * 1024 + col]);
}

// ---------------- zero the sync flags ----------------
__global__ __launch_bounds__(256) void k_zero(unsigned int* __restrict__ p,
                                              int n) {
  int i = blockIdx.x * 256 + threadIdx.x;
  if (i < n) p[i] = 0u;
}

// ---------------- MFMA f16 GEMM ----------------
// out_mode: 0 = f32 row-major, 1 = f16 row-major, 2 = f16 LSTM staging layout
// [t][slice8][gate4][b64][u32] (M must be 16384 rows = b*256+t, N=1024).
__global__ __launch_bounds__(256) void k_mgemm(
    const __half* __restrict__ A16, const __half* __restrict__ BT,
    const float* __restrict__ bias, void* __restrict__ out,
    int N, int K, int lda, int a_embed, int act_tanh, int out_mode,
    EmbArgs ea) {
  __shared__ _Float16 As[128 * 40];
  __shared__ _Float16 Bs[128 * 40];
  int tid = threadIdx.x;
  int lane = tid & 63, wave = tid >> 6;
  int wm = wave & 1, wn = wave >> 1;
  int col0 = blockIdx.x * 128, row0 = blockIdx.y * 128;

  f32x4 acc[4][4];
#pragma unroll
  for (int i = 0; i < 4; ++i)
#pragma unroll
    for (int j = 0; j < 4; ++j) acc[i][j] = (f32x4)0.0f;

  for (int kt = 0; kt < K; kt += 32) {
    __syncthreads();
#pragma unroll
    for (int it = 0; it < 2; ++it) {
      int lin = tid + it * 256;
      int r = lin & 127, kh8 = (lin >> 7) * 8;
      f16x8 va;
      if (!a_embed) {
        va = *(const f16x8*)(A16 + (size_t)(row0 + r) * lda + kt + kh8);
      } else {
        int row = row0 + r;
        int k0 = kt + kh8;
        if (k0 >= 912) {
          va = (f16x8)(_Float16)0.0f;
        } else {
          const float* src;
          if (k0 < 768) {
            src = ea.tf + (size_t)row * 768 + k0;
          } else {
            int b_ = row >> 8, t_ = row & 255;
            if (k0 < 800) src = ea.pos_tab + ea.pos_ids[row] * 32 + (k0 - 768);
            else if (k0 < 832) src = ea.dep_tab + ea.dep_ids[row] * 32 + (k0 - 800);
            else if (k0 < 864) {
              int d = t_ - ea.e1[b_] + 10; d = d < 0 ? 0 : (d > 20 ? 20 : d);
              src = ea.dist_tab + d * 32 + (k0 - 832);
            } else if (k0 < 896) {
              int d = t_ - ea.e2[b_] + 10; d = d < 0 ? 0 : (d > 20 ? 20 : d);
              src = ea.dist_tab + d * 32 + (k0 - 864);
            } else {
              src = ea.sdp_tab + ea.sdp[row] * 16 + (k0 - 896);
            }
          }
          float4 a = *(const float4*)src;
          float4 b2 = *(const float4*)(src + 4);
          va[0] = (_Float16)a.x;  va[1] = (_Float16)a.y;
          va[2] = (_Float16)a.z;  va[3] = (_Float16)a.w;
          va[4] = (_Float16)b2.x; va[5] = (_Float16)b2.y;
          va[6] = (_Float16)b2.z; va[7] = (_Float16)b2.w;
        }
      }
      *(f16x8*)&As[r * 40 + kh8] = va;
      f16x8 vb = *(const f16x8*)(BT + (size_t)(col0 + r) * K + kt + kh8);
      *(f16x8*)&Bs[r * 40 + kh8] = vb;
    }
    __syncthreads();
    f16x8 af[4], bf[4];
    int kq = (lane >> 4) * 8;
#pragma unroll
    for (int mt = 0; mt < 4; ++mt)
      af[mt] = *(const f16x8*)&As[(wm * 64 + mt * 16 + (lane & 15)) * 40 + kq];
#pragma unroll
    for (int nt = 0; nt < 4; ++nt)
      bf[nt] = *(const f16x8*)&Bs[(wn * 64 + nt * 16 + (lane & 15)) * 40 + kq];
#pragma unroll
    for (int mt = 0; mt < 4; ++mt)
#pragma unroll
      for (int nt = 0; nt < 4; ++nt)
        acc[mt][nt] = __builtin_amdgcn_mfma_f32_16x16x32_f16(
            af[mt], bf[nt], acc[mt][nt], 0, 0, 0);
  }

#pragma unroll
  for (int mt = 0; mt < 4; ++mt) {
#pragma unroll
    for (int nt = 0; nt < 4; ++nt) {
      int col = col0 + wn * 64 + nt * 16 + (lane & 15);
      float bv = bias[col];
#pragma unroll
      for (int r = 0; r < 4; ++r) {
        int row = row0 + wm * 64 + mt * 16 + (lane >> 4) * 4 + r;
        float v = acc[mt][nt][r] + bv;
        if (act_tanh) v = tanhf(v);
        if (out_mode == 0) {
          ((float*)out)[(size_t)row * N + col] = v;
        } else if (out_mode == 1) {
          ((__half*)out)[(size_t)row * N + col] = __float2half_rn(v);
        } else {
          // LSTM staging: [t][slice8][gate4][b][32 units]
          int b_ = row >> 8, t_ = row & 255;
          int g_ = col >> 8, u_ = col & 255;
          int sl = u_ >> 5, ul = u_ & 31;
          ((__half*)out)[((((size_t)(t_ * 8 + sl) * 4 + g_) * 64 + b_) * 32) + ul] =
              __float2half_rn(v);
        }
      }
    }
  }
}

// ---------------- BiLSTM v5 (round 9, unchanged) ----------------
__global__ __launch_bounds__(256, 1) void k_lstm3(
    const __half* __restrict__ XFs, const __half* __restrict__ XBs,
    const __half* __restrict__ WBf, const __half* __restrict__ WBb,
    __half* __restrict__ HexS, unsigned int* __restrict__ flags,
    __half* __restrict__ XT) {
  int bx = blockIdx.x;          // 0..15
  int dir = bx >> 3, slice = bx & 7;
  int tid = threadIdx.x;
  int lane = tid & 63, wave = tid >> 6;
  const __half* xWs = dir ? XBs : XFs;
  const __half* WB = dir ? WBb : WBf;
  __half* hexd = HexS + (size_t)dir * 256 * 16384;  // [step][slice8][b64][u32]
  unsigned int* flg = flags + dir * 2048;           // [slice][step]

  __shared__ _Float16 H[64 * 266];   // [b][u], row stride 266 f16
  __shared__ float GT[64 * 133];     // [b][c], row stride 133 dw (c=ul*4+g)

  f16x8 bfrag[2][8];
#pragma unroll
  for (int nt2 = 0; nt2 < 2; ++nt2) {
    int c = (wave * 2 + nt2) * 16 + (lane & 15);
#pragma unroll
    for (int kt = 0; kt < 8; ++kt)
      bfrag[nt2][kt] = *(const f16x8*)(
          WB + ((size_t)(slice * 128 + c) * 256) + kt * 32 + (lane >> 4) * 8);
  }
  for (int i = tid; i < 64 * 266 / 8; i += 256)
    ((f16x8*)H)[i] = (f16x8)(_Float16)0.0f;
  float cst[8];
#pragma unroll
  for (int p = 0; p < 8; ++p) cst[p] = 0.0f;
  int b_own = tid >> 2;
  int uc = tid & 3;   // 8-unit chunk within the 32-unit slice
  __syncthreads();

  for (int s = 0; s < 256; ++s) {
    int t = dir ? (255 - s) : s;
    const __half* xwp = xWs + ((size_t)(t * 8 + slice) * 8192) + tid * 8;
    f16x8 xwg[4];
#pragma unroll
    for (int g = 0; g < 4; ++g) xwg[g] = *(const f16x8*)(xwp + g * 2048);

    f32x4 acc[4][2];
#pragma unroll
    for (int mt = 0; mt < 4; ++mt)
#pragma unroll
      for (int nt2 = 0; nt2 < 2; ++nt2) acc[mt][nt2] = (f32x4)0.0f;
#pragma unroll
    for (int kt = 0; kt < 8; ++kt) {
      f16x8 a[4];
#pragma unroll
      for (int mt = 0; mt < 4; ++mt)
        a[mt] = *(const f16x8*)&H[(mt * 16 + (lane & 15)) * 266 + kt * 32 +
                                  (lane >> 4) * 8];
#pragma unroll
      for (int mt = 0; mt < 4; ++mt)
#pragma unroll
        for (int nt2 = 0; nt2 < 2; ++nt2)
          acc[mt][nt2] = __builtin_amdgcn_mfma_f32_16x16x32_f16(
              a[mt], bfrag[nt2][kt], acc[mt][nt2], 0, 0, 0);
    }
    __syncthreads();
#pragma unroll
    for (int mt = 0; mt < 4; ++mt)
#pragma unroll
      for (int nt2 = 0; nt2 < 2; ++nt2) {
        int col = (wave * 2 + nt2) * 16 + (lane & 15);
#pragma unroll
        for (int r = 0; r < 4; ++r) {
          int b = mt * 16 + (lane >> 4) * 4 + r;
          GT[b * 133 + col] = acc[mt][nt2][r];
        }
      }
    __syncthreads();
    PK hv;
#pragma unroll
    for (int p = 0; p < 8; ++p) {
      int ul = uc * 8 + p;
      float4 g4 = *(const float4*)&GT[b_own * 133 + 4 * ul];
      float gi = g4.x + (float)xwg[0][p];
      float gf = g4.y + (float)xwg[1][p];
      float gg = g4.z + (float)xwg[2][p];
      float go = g4.w + (float)xwg[3][p];
      cst[p] = sigm(gf) * cst[p] + sigm(gi) * tanhf(gg);
      float hn = sigm(go) * tanhf(cst[p]);
      hv.h[p] = (_Float16)hn;
    }
    *(f16x8*)&H[b_own * 266 + slice * 32 + uc * 8] = hv.v;

    if (s < 255) {
      __half* hexq = hexd + (size_t)s * 16384;
      unsigned long long* dst =
          (unsigned long long*)(hexq + slice * 2048 + tid * 8);
      __hip_atomic_store(&dst[0], hv.u64[0], __ATOMIC_RELAXED,
                         __HIP_MEMORY_SCOPE_AGENT);
      __hip_atomic_store(&dst[1], hv.u64[1], __ATOMIC_RELAXED,
                         __HIP_MEMORY_SCOPE_AGENT);
      asm volatile("s_waitcnt vmcnt(0)" ::: "memory");
      __syncthreads();
      if (tid == 0)
        __hip_atomic_store(&flg[(slice << 8) + s], 1u, __ATOMIC_RELAXED,
                           __HIP_MEMORY_SCOPE_AGENT);
      *(f16x8*)(XT + (size_t)((b_own << 8) + t) * 544 + dir * 256 +
                slice * 32 + uc * 8) = hv.v;
      if (tid < 8 && tid != slice) {
        while (__hip_atomic_load(&flg[(tid << 8) + s], __ATOMIC_RELAXED,
                                 __HIP_MEMORY_SCOPE_AGENT) == 0u)
          __builtin_amdgcn_s_sleep(1);
      }
      __syncthreads();
#pragma unroll
      for (int i = 0; i < 7; ++i) {
        int ps = i + (i >= slice ? 1 : 0);
        f16x8 pv = *(const f16x8*)(hexq + ps * 2048 + tid * 8);
        *(f16x8*)&H[b_own * 266 + ps * 32 + uc * 8] = pv;
      }
      __syncthreads();
    } else {
      *(f16x8*)(XT + (size_t)((b_own << 8) + t) * 544 + dir * 256 +
                slice * 32 + uc * 8) = hv.v;
    }
  }
}

// ---------------- fill dep_emb into x_tree cols [512,544), f16 -------------
__global__ __launch_bounds__(256) void k_depfill(
    const int* __restrict__ dep_ids, const float* __restrict__ dep_tab,
    __half* __restrict__ XT) {
  int e = blockIdx.x * 256 + threadIdx.x;  // 0..524287
  int row = e >> 5, k = e & 31;
  XT[(size_t)row * 544 + 512 + k] = __float2half_rn(dep_tab[dep_ids[row] * 32 + k]);
}

// ---------------- persistent tree + classifier: 1 block per batch ----------
// Thread j owns unit j for every node (c column is thread-private => no sync
// needed on Cg). h ping-pong in LDS f16: hA (<=128 nodes), hB (<=64).
// Levels: leaves(128..255) -> plo 64,32,16,8,4,2,1 -> root 0 (child 0 masked).
__global__ __launch_bounds__(256, 1) void k_tree(
    const float* __restrict__ XWIOU, const float* __restrict__ XWF,
    const float* __restrict__ Uiou, const float* __restrict__ Uf,
    float* __restrict__ Cg, float* __restrict__ Hall,
    const int* __restrict__ root_idx,
    const float* __restrict__ W1, const float* __restrict__ b1,
    const float* __restrict__ W2, const float* __restrict__ b2,
    float* __restrict__ out) {
  int b = blockIdx.x, j = threadIdx.x;
  __shared__ _Float16 hA[128 * 256];   // 64 KB
  __shared__ _Float16 hB[64 * 256];    // 32 KB
  size_t base = (size_t)(b << 8);

  // ---- leaves: nodes 128..255 -> hA slot = node-128
  for (int i = 0; i < 128; ++i) {
    size_t row = base + 128 + i;
    float iv = XWIOU[row * 768 + j];
    float ov = XWIOU[row * 768 + 256 + j];
    float uv = XWIOU[row * 768 + 512 + j];
    float c = sigm(iv) * tanhf(uv);
    float h = sigm(ov) * tanhf(c);
    Cg[row * 256 + j] = c;
    Hall[row * 256 + j] = h;
    hA[i * 256 + j] = (_Float16)h;
  }
  __syncthreads();

  _Float16* P = hA;
  _Float16* Q = hB;
  const int plos[8] = {64, 32, 16, 8, 4, 2, 1, 0};
  for (int lvl = 0; lvl < 8; ++lvl) {
    int plo = plos[lvl];
    int npar = (lvl == 7) ? 1 : plo;
    for (int c0 = 0; c0 < npar; c0 += 16) {
      int nc = npar - c0; if (nc > 16) nc = 16;
      float aI[16], aO[16], aU[16], aF0[16], aF1[16];
#pragma unroll
      for (int q = 0; q < 16; ++q) {
        aI[q] = 0.f; aO[q] = 0.f; aU[q] = 0.f; aF0[q] = 0.f; aF1[q] = 0.f;
      }
      for (int k = 0; k < 256; k += 2) {
        float wI0 = Uiou[(size_t)k * 768 + j];
        float wI1 = Uiou[(size_t)(k + 1) * 768 + j];
        float wO0 = Uiou[(size_t)k * 768 + 256 + j];
        float wO1 = Uiou[(size_t)(k + 1) * 768 + 256 + j];
        float wU0 = Uiou[(size_t)k * 768 + 512 + j];
        float wU1 = Uiou[(size_t)(k + 1) * 768 + 512 + j];
        float wF0 = Uf[(size_t)k * 256 + j];
        float wF1 = Uf[(size_t)(k + 1) * 256 + j];
#pragma unroll
        for (int q = 0; q < 16; ++q) {
          if (q < nc) {
            int i = c0 + q;
            float h0a, h0b, h1a, h1b;
            if (lvl < 7) {
              h2v x0 = *(const h2v*)&P[(2 * i) * 256 + k];
              h2v x1 = *(const h2v*)&P[(2 * i + 1) * 256 + k];
              h0a = (float)x0[0]; h0b = (float)x0[1];
              h1a = (float)x1[0]; h1b = (float)x1[1];
            } else {
              h2v x1 = *(const h2v*)&P[k];
              h0a = 0.f; h0b = 0.f;
              h1a = (float)x1[0]; h1b = (float)x1[1];
            }
            float sa = h0a + h1a, sb = h0b + h1b;
            aI[q] += sa * wI0 + sb * wI1;
            aO[q] += sa * wO0 + sb * wO1;
            aU[q] += sa * wU0 + sb * wU1;
            aF0[q] += h0a * wF0 + h0b * wF1;
            aF1[q] += h1a * wF0 + h1b * wF1;
          }
        }
      }
#pragma unroll
      for (int q = 0; q < 16; ++q) {
        if (q < nc) {
          int i = c0 + q, p = plo + i;
          size_t prow = base + p;
          float iv = XWIOU[prow * 768 + j] + aI[q];
          float ov = XWIOU[prow * 768 + 256 + j] + aO[q];
          float uv = XWIOU[prow * 768 + 512 + j] + aU[q];
          float xwf = XWF[prow * 256 + j];
          float fc;
          if (lvl < 7) {
            float cv0 = Cg[(base + 2 * p) * 256 + j];
            float cv1 = Cg[(base + 2 * p + 1) * 256 + j];
            fc = sigm(xwf + aF0[q]) * cv0 + sigm(xwf + aF1[q]) * cv1;
          } else {
            float cv1 = Cg[(base + 1) * 256 + j];
            fc = sigm(xwf + aF1[q]) * cv1;
          }
          float cnew = sigm(iv) * tanhf(uv) + fc;
          float hnew = sigm(ov) * tanhf(cnew);
          Cg[prow * 256 + j] = cnew;
          Hall[prow * 256 + j] = hnew;
          Q[i * 256 + j] = (_Float16)hnew;
        }
      }
    }
    __syncthreads();
    _Float16* tp = P; P = Q; Q = tp;
  }

  // ---- classifier (reuse LDS)
  float* hroot = (float*)hA;
  float* hid = hroot + 256;
  int root = root_idx[b];
  hroot[j] = Hall[(base + root) * 256 + j];
  __syncthreads();
  float acc = b1[j];
  for (int k = 0; k < 256; ++k) acc += hroot[k] * W1[k * 256 + j];
  hid[j] = fmaxf(acc, 0.0f);
  __syncthreads();
  if (j < 10) {
    float o = b2[j];
    for (int k = 0; k < 256; ++k) o += hid[k] * W2[k * 10 + j];
    out[b * 10 + j] = o;
  }
}

// ---------------------------------------------------------------------------
extern "C" void kernel_launch(void* const* d_in, const int* in_sizes, int n_in,
                              void* d_out, int out_size, void* d_ws,
                              size_t ws_size, hipStream_t stream) {
  (void)in_sizes; (void)n_in; (void)out_size; (void)ws_size;
  const float* tf       = (const float*)d_in[0];
  const int*   pos_ids  = (const int*)d_in[1];
  const int*   dep_ids  = (const int*)d_in[2];
  const int*   e1       = (const int*)d_in[3];
  const int*   e2       = (const int*)d_in[4];
  const int*   sdp      = (const int*)d_in[5];
  const int*   heads    = (const int*)d_in[6];
  const int*   root     = (const int*)d_in[7];
  const float* pos_tab  = (const float*)d_in[8];
  const float* dep_tab  = (const float*)d_in[9];
  const float* dist_tab = (const float*)d_in[10];
  const float* sdp_tab  = (const float*)d_in[11];
  const float* W_ft     = (const float*)d_in[12];
  const float* b_ft     = (const float*)d_in[13];
  const float* Wih_f    = (const float*)d_in[14];
  const float* Whh_f    = (const float*)d_in[15];
  const float* bl_f     = (const float*)d_in[16];
  const float* Wih_b    = (const float*)d_in[17];
  const float* Whh_b    = (const float*)d_in[18];
  const float* bl_b     = (const float*)d_in[19];
  const float* W_iou    = (const float*)d_in[20];
  const float* U_iou    = (const float*)d_in[21];
  const float* b_iou    = (const float*)d_in[22];
  const float* Wf_t     = (const float*)d_in[23];
  const float* Uf_t     = (const float*)d_in[24];
  const float* bf_t     = (const float*)d_in[25];
  const float* W1       = (const float*)d_in[26];
  const float* b1       = (const float*)d_in[27];
  const float* W2       = (const float*)d_in[28];
  const float* b2       = (const float*)d_in[29];
  (void)heads;

  // ---- workspace (lifetime-overlaid; peak < proven-safe 122.7 MB)
  char* ws = (char*)d_ws;
  __half* XF    = (__half*)(ws + 0ull);            // 33.5MB  phase2->3 (staged layout)
  __half* XB    = (__half*)(ws + 33554432ull);     // 33.5MB  phase2->3 (staged layout)
  float*  XWIOU = (float*)(ws + 0ull);             // 50.3MB  phase5->6
  float*  XWF   = (float*)(ws + 50331648ull);      // 16.8MB  phase5->6
  __half* XT    = (__half*)(ws + 67108864ull);     // 17.8MB  phase3->5
  float*  H     = (float*)(ws + 88080384ull);      // 16.8MB  phase6 (Hall)
  __half* T     = (__half*)(ws + 88080384ull);     // 16.8MB  phase1->2 (over H)
  __half* HexS  = (__half*)(ws + 88080384ull);     // 16.8MB  phase3 (over T/H)
  float*  C     = (float*)(ws + 104857600ull);     // 16.8MB  phase6 (Cg)
  // packs live inside C region (dead before C written):
  __half* BTft  = (__half*)(ws + 104857600ull);    // 950,272
  __half* BTwhf = (__half*)(ws + 105807872ull);    // 1,048,576
  __half* BTwhb = (__half*)(ws + 106856448ull);    // 1,048,576
  __half* BTiou = (__half*)(ws + 107905024ull);    // 835,584
  __half* BTf   = (__half*)(ws + 108740608ull);    // 278,528
  __half* WBf   = (__half*)(ws + 109019136ull);    // 524,288
  __half* WBb   = (__half*)(ws + 109543424ull);    // 524,288
  unsigned int* FLG = (unsigned int*)(ws + 110198784ull);  // 16,384

  EmbArgs ea{tf, pos_ids, dep_ids, e1, e2, sdp, pos_tab, dep_tab, dist_tab, sdp_tab};

  // 0. weight packs + flag zero
  k_packB<<<dim3(912, 2), dim3(256), 0, stream>>>(W_ft, BTft, 512, 928);
  k_zft<<<dim3(32), dim3(256), 0, stream>>>(BTft);
  k_packB<<<dim3(512, 4), dim3(256), 0, stream>>>(Wih_f, BTwhf, 1024, 512);
  k_packB<<<dim3(512, 4), dim3(256), 0, stream>>>(Wih_b, BTwhb, 1024, 512);
  k_packB<<<dim3(544, 3), dim3(256), 0, stream>>>(W_iou, BTiou, 768, 544);
  k_packB<<<dim3(544, 1), dim3(256), 0, stream>>>(Wf_t, BTf, 256, 544);
  k_packWB<<<dim3(1024), dim3(256), 0, stream>>>(Whh_f, WBf);
  k_packWB<<<dim3(1024), dim3(256), 0, stream>>>(Whh_b, WBb);
  k_zero<<<dim3(16), dim3(256), 0, stream>>>(FLG, 4096);

  // 1. T = tanh(embed @ W_ft + b_ft)  [f16 out, embed fused]
  k_mgemm<<<dim3(4, 128), dim3(256), 0, stream>>>(
      nullptr, BTft, b_ft, (void*)T, 512, 928, 0, 1, 1, 1, ea);
  // 2. xW_f / xW_b  [f16 out, LSTM staging layout]
  k_mgemm<<<dim3(8, 128), dim3(256), 0, stream>>>(
      T, BTwhf, bl_f, (void*)XF, 1024, 512, 512, 0, 0, 2, ea);
  k_mgemm<<<dim3(8, 128), dim3(256), 0, stream>>>(
      T, BTwhb, bl_b, (void*)XB, 1024, 512, 512, 0, 0, 2, ea);
  // 3. BiLSTM -> XT cols [0,512)   (HexS overlays dead T)
  k_lstm3<<<dim3(16), dim3(256), 0, stream>>>(XF, XB, WBf, WBb, HexS, FLG, XT);
  // 4. dep_emb -> XT cols [512,544)
  k_depfill<<<dim3(2048), dim3(256), 0, stream>>>(dep_ids, dep_tab, XT);
  // 5. xWiou / xWf  [f32 out]
  k_mgemm<<<dim3(6, 128), dim3(256), 0, stream>>>(
      XT, BTiou, b_iou, (void*)XWIOU, 768, 544, 544, 0, 0, 0, ea);
  k_mgemm<<<dim3(2, 128), dim3(256), 0, stream>>>(
      XT, BTf, bf_t, (void*)XWF, 256, 544, 544, 0, 0, 0, ea);
  // 6. persistent tree + classifier (one block per batch)
  k_tree<<<dim3(64), dim3(256), 0, stream>>>(
      XWIOU, XWF, U_iou, Uf_t, C, H, root, W1, b1, W2, b2, (float*)d_out);
}